// Round 3
// baseline (582.882 us; speedup 1.0000x reference)
//
#include <hip/hip_runtime.h>

#define NUM_USERS 50000
#define NUM_ITEMS 100000
#define NUM_NODES 150000   // NUM_USERS + NUM_ITEMS
#define D 64
#define NNZ 4800000
#define BATCH 4096
// light_out = acc / (N_LAYERS+1) = acc/4 ; gamma = (acc_u/4)·(acc_i/4) = dot/16

// ---------------------------------------------------------------------------
// k_init: cur = acc = concat(user_emb, item_emb), vectorized float4
// ---------------------------------------------------------------------------
__global__ void k_init(const float* __restrict__ ue, const float* __restrict__ ie,
                       float* __restrict__ cur, float* __restrict__ acc) {
    const int total = NUM_NODES * D / 4;     // 2.4M float4
    const int ulim  = NUM_USERS * D / 4;
    const float4* u4 = (const float4*)ue;
    const float4* i4 = (const float4*)ie;
    float4* c4 = (float4*)cur;
    float4* a4 = (float4*)acc;
    for (int i = blockIdx.x * blockDim.x + threadIdx.x; i < total;
         i += gridDim.x * blockDim.x) {
        float4 v = (i < ulim) ? u4[i] : i4[i - ulim];
        c4[i] = v;
        a4[i] = v;
    }
}

// ---------------------------------------------------------------------------
// k_rowptr: rowptr[r] = lower_bound(rows, r)  (rows is sorted)
// ---------------------------------------------------------------------------
__global__ void k_rowptr(const int* __restrict__ rows, int* __restrict__ rowptr) {
    int r = blockIdx.x * blockDim.x + threadIdx.x;
    if (r > NUM_NODES) return;
    int lo = 0, hi = NNZ;
    while (lo < hi) {
        int mid = (lo + hi) >> 1;
        if (rows[mid] < r) lo = mid + 1; else hi = mid;
    }
    rowptr[r] = lo;
}

// ---------------------------------------------------------------------------
// k_spmm: 16 lanes per row (float4 per lane), 4 rows per wave.
// Explicit 3-phase staging per 16-edge batch:
//   1) 32 shfl broadcasts -> c[16], v[16] in registers
//   2) 16 independent float4 gathers -> xv[16] (all in flight at once)
//   3) 16 FMA quads
// Fully unrolled => compile-time indices => register-resident (no scratch).
// Tail edges padded with c=0,v=0 (hits hot row-0 line, adds zero).
// ---------------------------------------------------------------------------
template <bool WRITE_NEXT>
__global__ __launch_bounds__(256) void k_spmm(const int* __restrict__ rowptr,
                       const int* __restrict__ cols,
                       const float* __restrict__ vals,
                       const float* __restrict__ x,
                       float* __restrict__ nxt,
                       float* __restrict__ acc) {
    const int wid   = (blockIdx.x * blockDim.x + threadIdx.x) >> 6;
    const int lane  = threadIdx.x & 63;
    const int l16   = lane & 15;
    const int gbase = lane & 48;           // 16-lane group base for shfl
    const int row   = wid * 4 + (lane >> 4);
    if (row >= NUM_NODES) return;          // group-uniform exit
    const int e0 = rowptr[row];
    const int e1 = rowptr[row + 1];
    const float4* __restrict__ x4 = (const float4*)x;
    float4 sum = make_float4(0.f, 0.f, 0.f, 0.f);
    for (int e = e0; e < e1; e += 16) {
        const int  idx = e + l16;
        const bool ok  = idx < e1;
        int   myc = ok ? cols[idx] : 0;
        float myv = ok ? vals[idx] : 0.f;
        int   c[16];
        float v[16];
#pragma unroll
        for (int t = 0; t < 16; ++t) {
            c[t] = __shfl(myc, gbase + t);
            v[t] = __shfl(myv, gbase + t);
        }
        float4 xv[16];
#pragma unroll
        for (int t = 0; t < 16; ++t)
            xv[t] = x4[(size_t)c[t] * 16 + l16];   // 16 gathers in flight
#pragma unroll
        for (int t = 0; t < 16; ++t) {
            sum.x += v[t] * xv[t].x;  sum.y += v[t] * xv[t].y;
            sum.z += v[t] * xv[t].z;  sum.w += v[t] * xv[t].w;
        }
    }
    const size_t o = (size_t)row * 16 + l16;
    if (WRITE_NEXT) ((float4*)nxt)[o] = sum;
    float4* acc4 = (float4*)acc;
    float4 a = acc4[o];
    a.x += sum.x; a.y += sum.y; a.z += sum.z; a.w += sum.w;
    acc4[o] = a;
}

// ---------------------------------------------------------------------------
// k_gamma: one wave per batch element; 64-lane dot + shuffle reduce; /16
// ---------------------------------------------------------------------------
__global__ void k_gamma(const float* __restrict__ acc,
                        const int* __restrict__ users,
                        const int* __restrict__ items,
                        float* __restrict__ out) {
    int wid  = (blockIdx.x * blockDim.x + threadIdx.x) >> 6;
    int lane = threadIdx.x & 63;
    if (wid >= BATCH) return;
    int u  = users[wid];
    int it = items[wid];
    float a = acc[(size_t)u * D + lane];
    float b = acc[((size_t)NUM_USERS + it) * D + lane];
    float p = a * b;
    for (int off = 32; off; off >>= 1) p += __shfl_down(p, off);
    if (lane == 0) out[wid] = p * (1.0f / 16.0f);
}

extern "C" void kernel_launch(void* const* d_in, const int* in_sizes, int n_in,
                              void* d_out, int out_size, void* d_ws, size_t ws_size,
                              hipStream_t stream) {
    const float* ue    = (const float*)d_in[0];
    const float* ie    = (const float*)d_in[1];
    const int*   rows  = (const int*)d_in[2];
    const int*   cols  = (const int*)d_in[3];
    const float* vals  = (const float*)d_in[4];
    const int*   users = (const int*)d_in[5];
    const int*   items = (const int*)d_in[6];
    float*       out   = (float*)d_out;

    // workspace layout: rowptr | bufA | bufB | acc
    char* ws = (char*)d_ws;
    size_t off = (((size_t)(NUM_NODES + 1) * sizeof(int)) + 255) & ~(size_t)255;
    int*   rowptr = (int*)ws;
    float* bufA   = (float*)(ws + off);
    float* bufB   = (float*)(ws + off + 1ull * NUM_NODES * D * sizeof(float));
    float* acc    = (float*)(ws + off + 2ull * NUM_NODES * D * sizeof(float));

    k_rowptr<<<(NUM_NODES + 1 + 255) / 256, 256, 0, stream>>>(rows, rowptr);
    k_init<<<2048, 256, 0, stream>>>(ue, ie, bufA, acc);

    // 3 SpMM layers; 4 rows per wave, 4 waves per block -> 16 rows/block
    const int spmm_blocks = NUM_NODES / 16;   // 150000/16 = 9375 exact
    k_spmm<true ><<<spmm_blocks, 256, 0, stream>>>(rowptr, cols, vals, bufA, bufB, acc);
    k_spmm<true ><<<spmm_blocks, 256, 0, stream>>>(rowptr, cols, vals, bufB, bufA, acc);
    k_spmm<false><<<spmm_blocks, 256, 0, stream>>>(rowptr, cols, vals, bufA, nullptr, acc);

    k_gamma<<<(BATCH * 64) / 256, 256, 0, stream>>>(acc, users, items, out);
}

// Round 4
// 553.896 us; speedup vs baseline: 1.0523x; 1.0523x over previous
//
#include <hip/hip_runtime.h>

#define NUM_USERS 50000
#define NUM_ITEMS 100000
#define NUM_NODES 150000   // NUM_USERS + NUM_ITEMS
#define D 64
#define NNZ 4800000
#define BATCH 4096
// light_out = acc / (N_LAYERS+1) = acc/4 ; gamma = (acc_u/4)·(acc_i/4) = dot/16

// ---------------------------------------------------------------------------
// k_init: cur = acc = concat(user_emb, item_emb), vectorized float4
// ---------------------------------------------------------------------------
__global__ void k_init(const float* __restrict__ ue, const float* __restrict__ ie,
                       float* __restrict__ cur, float* __restrict__ acc) {
    const int total = NUM_NODES * D / 4;     // 2.4M float4
    const int ulim  = NUM_USERS * D / 4;
    const float4* u4 = (const float4*)ue;
    const float4* i4 = (const float4*)ie;
    float4* c4 = (float4*)cur;
    float4* a4 = (float4*)acc;
    for (int i = blockIdx.x * blockDim.x + threadIdx.x; i < total;
         i += gridDim.x * blockDim.x) {
        float4 v = (i < ulim) ? u4[i] : i4[i - ulim];
        c4[i] = v;
        a4[i] = v;
    }
}

// ---------------------------------------------------------------------------
// k_rowptr: rowptr[r] = lower_bound(rows, r)  (rows is sorted)
// ---------------------------------------------------------------------------
__global__ void k_rowptr(const int* __restrict__ rows, int* __restrict__ rowptr) {
    int r = blockIdx.x * blockDim.x + threadIdx.x;
    if (r > NUM_NODES) return;
    int lo = 0, hi = NNZ;
    while (lo < hi) {
        int mid = (lo + hi) >> 1;
        if (rows[mid] < r) lo = mid + 1; else hi = mid;
    }
    rowptr[r] = lo;
}

// ---------------------------------------------------------------------------
// k_spmm: 16 lanes per row (float4 per lane), 4 rows per wave.
// Per 16-edge batch:
//   1) shfl-broadcast c[16], v[16]
//   2) predicated prefetch of NEXT batch's cols/vals (hides under gathers)
//   3) issue 16 independent float4 gathers
//   4) sched_barrier(0)  <- pins all 16 loads BEFORE the FMAs; without this
//      the compiler re-fuses into ~5-deep load/wait/FMA clusters (R3: VGPR=36)
//   5) 16 FMA quads
// ---------------------------------------------------------------------------
template <bool WRITE_NEXT>
__global__ __launch_bounds__(256, 4) void k_spmm(const int* __restrict__ rowptr,
                       const int* __restrict__ cols,
                       const float* __restrict__ vals,
                       const float* __restrict__ x,
                       float* __restrict__ nxt,
                       float* __restrict__ acc) {
    const int wid   = (blockIdx.x * blockDim.x + threadIdx.x) >> 6;
    const int lane  = threadIdx.x & 63;
    const int l16   = lane & 15;
    const int gbase = lane & 48;           // 16-lane group base for shfl
    const int row   = wid * 4 + (lane >> 4);
    if (row >= NUM_NODES) return;          // group-uniform exit
    const int e0 = rowptr[row];
    const int e1 = rowptr[row + 1];
    const float4* __restrict__ x4 = (const float4*)x;
    float4 sum = make_float4(0.f, 0.f, 0.f, 0.f);

    // batch-0 metadata
    int   idx0 = e0 + l16;
    bool  ok0  = idx0 < e1;
    int   myc  = ok0 ? cols[idx0] : 0;
    float myv  = ok0 ? vals[idx0] : 0.f;

    for (int e = e0; e < e1; e += 16) {
        int   c[16];
        float v[16];
#pragma unroll
        for (int t = 0; t < 16; ++t) {
            c[t] = __shfl(myc, gbase + t);
            v[t] = __shfl(myv, gbase + t);
        }
        // prefetch next batch's metadata; latency hides under the 16 gathers
        {
            int  idx2 = e + 16 + l16;
            bool ok2  = idx2 < e1;
            myc = ok2 ? cols[idx2] : 0;
            myv = ok2 ? vals[idx2] : 0.f;
        }
        float4 xv[16];
#pragma unroll
        for (int t = 0; t < 16; ++t)
            xv[t] = x4[(size_t)c[t] * 16 + l16];   // 16 gathers in flight
        __builtin_amdgcn_sched_barrier(0);          // do NOT sink loads past here
#pragma unroll
        for (int t = 0; t < 16; ++t) {
            sum.x += v[t] * xv[t].x;  sum.y += v[t] * xv[t].y;
            sum.z += v[t] * xv[t].z;  sum.w += v[t] * xv[t].w;
        }
    }
    const size_t o = (size_t)row * 16 + l16;
    if (WRITE_NEXT) ((float4*)nxt)[o] = sum;
    float4* acc4 = (float4*)acc;
    float4 a = acc4[o];
    a.x += sum.x; a.y += sum.y; a.z += sum.z; a.w += sum.w;
    acc4[o] = a;
}

// ---------------------------------------------------------------------------
// k_gamma: one wave per batch element; 64-lane dot + shuffle reduce; /16
// ---------------------------------------------------------------------------
__global__ void k_gamma(const float* __restrict__ acc,
                        const int* __restrict__ users,
                        const int* __restrict__ items,
                        float* __restrict__ out) {
    int wid  = (blockIdx.x * blockDim.x + threadIdx.x) >> 6;
    int lane = threadIdx.x & 63;
    if (wid >= BATCH) return;
    int u  = users[wid];
    int it = items[wid];
    float a = acc[(size_t)u * D + lane];
    float b = acc[((size_t)NUM_USERS + it) * D + lane];
    float p = a * b;
    for (int off = 32; off; off >>= 1) p += __shfl_down(p, off);
    if (lane == 0) out[wid] = p * (1.0f / 16.0f);
}

extern "C" void kernel_launch(void* const* d_in, const int* in_sizes, int n_in,
                              void* d_out, int out_size, void* d_ws, size_t ws_size,
                              hipStream_t stream) {
    const float* ue    = (const float*)d_in[0];
    const float* ie    = (const float*)d_in[1];
    const int*   rows  = (const int*)d_in[2];
    const int*   cols  = (const int*)d_in[3];
    const float* vals  = (const float*)d_in[4];
    const int*   users = (const int*)d_in[5];
    const int*   items = (const int*)d_in[6];
    float*       out   = (float*)d_out;

    // workspace layout: rowptr | bufA | bufB | acc
    char* ws = (char*)d_ws;
    size_t off = (((size_t)(NUM_NODES + 1) * sizeof(int)) + 255) & ~(size_t)255;
    int*   rowptr = (int*)ws;
    float* bufA   = (float*)(ws + off);
    float* bufB   = (float*)(ws + off + 1ull * NUM_NODES * D * sizeof(float));
    float* acc    = (float*)(ws + off + 2ull * NUM_NODES * D * sizeof(float));

    k_rowptr<<<(NUM_NODES + 1 + 255) / 256, 256, 0, stream>>>(rows, rowptr);
    k_init<<<2048, 256, 0, stream>>>(ue, ie, bufA, acc);

    // 3 SpMM layers; 4 rows per wave, 4 waves per block -> 16 rows/block
    const int spmm_blocks = NUM_NODES / 16;   // 150000/16 = 9375 exact
    k_spmm<true ><<<spmm_blocks, 256, 0, stream>>>(rowptr, cols, vals, bufA, bufB, acc);
    k_spmm<true ><<<spmm_blocks, 256, 0, stream>>>(rowptr, cols, vals, bufB, bufA, acc);
    k_spmm<false><<<spmm_blocks, 256, 0, stream>>>(rowptr, cols, vals, bufA, nullptr, acc);

    k_gamma<<<(BATCH * 64) / 256, 256, 0, stream>>>(acc, users, items, out);
}

// Round 5
// 295.889 us; speedup vs baseline: 1.9699x; 1.8720x over previous
//
#include <hip/hip_runtime.h>

#define NUM_USERS 50000
#define NUM_ITEMS 100000
#define NUM_NODES 150000   // NUM_USERS + NUM_ITEMS
#define D 64
#define NNZ 4800000
#define BATCH 4096
// light_out = acc / (N_LAYERS+1) = acc/4 ; gamma = (acc_u/4)·(acc_i/4) = dot/16

typedef __attribute__((ext_vector_type(4))) _Float16 half4;

// ---------------------------------------------------------------------------
// k_init: cur(fp16) = acc(fp32) = concat(user_emb, item_emb)
// ---------------------------------------------------------------------------
__global__ void k_init(const float* __restrict__ ue, const float* __restrict__ ie,
                       half4* __restrict__ cur, float* __restrict__ acc) {
    const int total = NUM_NODES * D / 4;     // 2.4M groups of 4
    const int ulim  = NUM_USERS * D / 4;
    const float4* u4 = (const float4*)ue;
    const float4* i4 = (const float4*)ie;
    float4* a4 = (float4*)acc;
    for (int i = blockIdx.x * blockDim.x + threadIdx.x; i < total;
         i += gridDim.x * blockDim.x) {
        float4 v = (i < ulim) ? u4[i] : i4[i - ulim];
        half4 h;
        h.x = (_Float16)v.x; h.y = (_Float16)v.y;
        h.z = (_Float16)v.z; h.w = (_Float16)v.w;
        cur[i] = h;
        a4[i] = v;
    }
}

// ---------------------------------------------------------------------------
// k_rowptr: rowptr[r] = lower_bound(rows, r)  (rows is sorted)
// ---------------------------------------------------------------------------
__global__ void k_rowptr(const int* __restrict__ rows, int* __restrict__ rowptr) {
    int r = blockIdx.x * blockDim.x + threadIdx.x;
    if (r > NUM_NODES) return;
    int lo = 0, hi = NNZ;
    while (lo < hi) {
        int mid = (lo + hi) >> 1;
        if (rows[mid] < r) lo = mid + 1; else hi = mid;
    }
    rowptr[r] = lo;
}

// ---------------------------------------------------------------------------
// k_spmm: 16 lanes per row, 4 rows/wave. x is fp16 [150000][64] -> one edge
// row = 128B = ONE cache line (halves MSHR demand + L3 traffic vs fp32).
// Accumulate fp32. Metadata shfl-broadcast per 16-edge batch + next-batch
// prefetch; sched_barrier pins the 16 gathers ahead of the FMAs.
// ---------------------------------------------------------------------------
template <bool WRITE_NEXT>
__global__ __launch_bounds__(256, 4) void k_spmm(const int* __restrict__ rowptr,
                       const int* __restrict__ cols,
                       const float* __restrict__ vals,
                       const half4* __restrict__ x,
                       half4* __restrict__ nxt,
                       float* __restrict__ acc) {
    const int wid   = (blockIdx.x * blockDim.x + threadIdx.x) >> 6;
    const int lane  = threadIdx.x & 63;
    const int l16   = lane & 15;
    const int gbase = lane & 48;           // 16-lane group base for shfl
    const int row   = wid * 4 + (lane >> 4);
    if (row >= NUM_NODES) return;          // group-uniform exit
    const int e0 = rowptr[row];
    const int e1 = rowptr[row + 1];
    float4 sum = make_float4(0.f, 0.f, 0.f, 0.f);

    // batch-0 metadata
    int   idx0 = e0 + l16;
    bool  ok0  = idx0 < e1;
    int   myc  = ok0 ? cols[idx0] : 0;
    float myv  = ok0 ? vals[idx0] : 0.f;

    for (int e = e0; e < e1; e += 16) {
        int   c[16];
        float v[16];
#pragma unroll
        for (int t = 0; t < 16; ++t) {
            c[t] = __shfl(myc, gbase + t);
            v[t] = __shfl(myv, gbase + t);
        }
        // prefetch next batch's metadata; hides under the gathers
        {
            int  idx2 = e + 16 + l16;
            bool ok2  = idx2 < e1;
            myc = ok2 ? cols[idx2] : 0;
            myv = ok2 ? vals[idx2] : 0.f;
        }
        half4 xv[16];
#pragma unroll
        for (int t = 0; t < 16; ++t)
            xv[t] = x[(size_t)c[t] * 16 + l16];   // 8B/lane, 128B per group
        __builtin_amdgcn_sched_barrier(0);         // keep gathers clustered
#pragma unroll
        for (int t = 0; t < 16; ++t) {
            sum.x += v[t] * (float)xv[t].x;
            sum.y += v[t] * (float)xv[t].y;
            sum.z += v[t] * (float)xv[t].z;
            sum.w += v[t] * (float)xv[t].w;
        }
    }
    const size_t o = (size_t)row * 16 + l16;
    if (WRITE_NEXT) {
        half4 h;
        h.x = (_Float16)sum.x; h.y = (_Float16)sum.y;
        h.z = (_Float16)sum.z; h.w = (_Float16)sum.w;
        nxt[o] = h;
    }
    float4* acc4 = (float4*)acc;
    float4 a = acc4[o];
    a.x += sum.x; a.y += sum.y; a.z += sum.z; a.w += sum.w;
    acc4[o] = a;
}

// ---------------------------------------------------------------------------
// k_gamma: one wave per batch element; 64-lane dot + shuffle reduce; /16
// ---------------------------------------------------------------------------
__global__ void k_gamma(const float* __restrict__ acc,
                        const int* __restrict__ users,
                        const int* __restrict__ items,
                        float* __restrict__ out) {
    int wid  = (blockIdx.x * blockDim.x + threadIdx.x) >> 6;
    int lane = threadIdx.x & 63;
    if (wid >= BATCH) return;
    int u  = users[wid];
    int it = items[wid];
    float a = acc[(size_t)u * D + lane];
    float b = acc[((size_t)NUM_USERS + it) * D + lane];
    float p = a * b;
    for (int off = 32; off; off >>= 1) p += __shfl_down(p, off);
    if (lane == 0) out[wid] = p * (1.0f / 16.0f);
}

extern "C" void kernel_launch(void* const* d_in, const int* in_sizes, int n_in,
                              void* d_out, int out_size, void* d_ws, size_t ws_size,
                              hipStream_t stream) {
    const float* ue    = (const float*)d_in[0];
    const float* ie    = (const float*)d_in[1];
    const int*   rows  = (const int*)d_in[2];
    const int*   cols  = (const int*)d_in[3];
    const float* vals  = (const float*)d_in[4];
    const int*   users = (const int*)d_in[5];
    const int*   items = (const int*)d_in[6];
    float*       out   = (float*)d_out;

    // workspace layout: rowptr | bufA(fp16) | bufB(fp16) | acc(fp32)
    char* ws = (char*)d_ws;
    size_t off = (((size_t)(NUM_NODES + 1) * sizeof(int)) + 255) & ~(size_t)255;
    const size_t halfbuf = (size_t)NUM_NODES * D * sizeof(_Float16); // 19.2 MB
    int*   rowptr = (int*)ws;
    half4* bufA   = (half4*)(ws + off);
    half4* bufB   = (half4*)(ws + off + halfbuf);
    float* acc    = (float*)(ws + off + 2 * halfbuf);

    k_rowptr<<<(NUM_NODES + 1 + 255) / 256, 256, 0, stream>>>(rows, rowptr);
    k_init<<<2048, 256, 0, stream>>>(ue, ie, bufA, acc);

    // 3 SpMM layers; 4 rows per wave, 4 waves per block -> 16 rows/block
    const int spmm_blocks = NUM_NODES / 16;   // 150000/16 = 9375 exact
    k_spmm<true ><<<spmm_blocks, 256, 0, stream>>>(rowptr, cols, vals, bufA, bufB, acc);
    k_spmm<true ><<<spmm_blocks, 256, 0, stream>>>(rowptr, cols, vals, bufB, bufA, acc);
    k_spmm<false><<<spmm_blocks, 256, 0, stream>>>(rowptr, cols, vals, bufA, nullptr, acc);

    k_gamma<<<(BATCH * 64) / 256, 256, 0, stream>>>(acc, users, items, out);
}

// Round 6
// 262.355 us; speedup vs baseline: 2.2217x; 1.1278x over previous
//
#include <hip/hip_runtime.h>

#define NUM_USERS 50000
#define NUM_ITEMS 100000
#define NUM_NODES 150000   // NUM_USERS + NUM_ITEMS
#define D 64
#define NNZ 4800000
#define BATCH 4096
// light_out = acc/4 ; gamma = (sum_k u_k)·(sum_k i_k)/16 — acc never materialized:
// keep x0..x3 (fp16) and sum the 8 needed rows per batch element in k_gamma.

typedef __attribute__((ext_vector_type(4))) _Float16 half4;

// ---------------------------------------------------------------------------
// k_init: x0(fp16) = concat(user_emb, item_emb)
// ---------------------------------------------------------------------------
__global__ void k_init(const float* __restrict__ ue, const float* __restrict__ ie,
                       half4* __restrict__ x0) {
    const int total = NUM_NODES * D / 4;     // 2.4M groups of 4
    const int ulim  = NUM_USERS * D / 4;
    const float4* u4 = (const float4*)ue;
    const float4* i4 = (const float4*)ie;
    for (int i = blockIdx.x * blockDim.x + threadIdx.x; i < total;
         i += gridDim.x * blockDim.x) {
        float4 v = (i < ulim) ? u4[i] : i4[i - ulim];
        half4 h;
        h.x = (_Float16)v.x; h.y = (_Float16)v.y;
        h.z = (_Float16)v.z; h.w = (_Float16)v.w;
        x0[i] = h;
    }
}

// ---------------------------------------------------------------------------
// k_rowptr: rowptr[r] = lower_bound(rows, r)  (rows is sorted)
// ---------------------------------------------------------------------------
__global__ void k_rowptr(const int* __restrict__ rows, int* __restrict__ rowptr) {
    int r = blockIdx.x * blockDim.x + threadIdx.x;
    if (r > NUM_NODES) return;
    int lo = 0, hi = NNZ;
    while (lo < hi) {
        int mid = (lo + hi) >> 1;
        if (rows[mid] < r) lo = mid + 1; else hi = mid;
    }
    rowptr[r] = lo;
}

// ---------------------------------------------------------------------------
// k_spmm: 16 lanes per row, 4 rows/wave. x fp16 [150000][64]: one edge row =
// 128B = ONE cache line. fp32 accumulate, fp16 store. Metadata shfl-broadcast
// per 16-edge batch + next-batch prefetch; sched_barrier pins the 16 gathers
// ahead of the FMAs. No acc RMW (removed: epilogue sums layer outputs).
// ---------------------------------------------------------------------------
__global__ __launch_bounds__(256, 4) void k_spmm(const int* __restrict__ rowptr,
                       const int* __restrict__ cols,
                       const float* __restrict__ vals,
                       const half4* __restrict__ x,
                       half4* __restrict__ nxt) {
    const int wid   = (blockIdx.x * blockDim.x + threadIdx.x) >> 6;
    const int lane  = threadIdx.x & 63;
    const int l16   = lane & 15;
    const int gbase = lane & 48;           // 16-lane group base for shfl
    const int row   = wid * 4 + (lane >> 4);
    if (row >= NUM_NODES) return;          // group-uniform exit
    const int e0 = rowptr[row];
    const int e1 = rowptr[row + 1];
    float4 sum = make_float4(0.f, 0.f, 0.f, 0.f);

    // batch-0 metadata
    int   idx0 = e0 + l16;
    bool  ok0  = idx0 < e1;
    int   myc  = ok0 ? cols[idx0] : 0;
    float myv  = ok0 ? vals[idx0] : 0.f;

    for (int e = e0; e < e1; e += 16) {
        int   c[16];
        float v[16];
#pragma unroll
        for (int t = 0; t < 16; ++t) {
            c[t] = __shfl(myc, gbase + t);
            v[t] = __shfl(myv, gbase + t);
        }
        // prefetch next batch's metadata; hides under the gathers
        {
            int  idx2 = e + 16 + l16;
            bool ok2  = idx2 < e1;
            myc = ok2 ? cols[idx2] : 0;
            myv = ok2 ? vals[idx2] : 0.f;
        }
        half4 xv[16];
#pragma unroll
        for (int t = 0; t < 16; ++t)
            xv[t] = x[(size_t)c[t] * 16 + l16];   // 8B/lane, 128B per group
        __builtin_amdgcn_sched_barrier(0);         // keep gathers clustered
#pragma unroll
        for (int t = 0; t < 16; ++t) {
            sum.x += v[t] * (float)xv[t].x;
            sum.y += v[t] * (float)xv[t].y;
            sum.z += v[t] * (float)xv[t].z;
            sum.w += v[t] * (float)xv[t].w;
        }
    }
    half4 h;
    h.x = (_Float16)sum.x; h.y = (_Float16)sum.y;
    h.z = (_Float16)sum.z; h.w = (_Float16)sum.w;
    nxt[(size_t)row * 16 + l16] = h;
}

// ---------------------------------------------------------------------------
// k_gamma: 16 lanes per batch element (half4/lane), 4 elements/wave.
// su = sum_k x_k[u], si = sum_k x_k[i] (fp32); gamma = dot(su,si)/16.
// ---------------------------------------------------------------------------
__global__ void k_gamma(const half4* __restrict__ x0, const half4* __restrict__ x1,
                        const half4* __restrict__ x2, const half4* __restrict__ x3,
                        const int* __restrict__ users, const int* __restrict__ items,
                        float* __restrict__ out) {
    const int wid  = (blockIdx.x * blockDim.x + threadIdx.x) >> 6;
    const int lane = threadIdx.x & 63;
    const int l16  = lane & 15;
    const int b    = wid * 4 + (lane >> 4);
    if (b >= BATCH) return;
    const size_t ur = (size_t)users[b] * 16 + l16;
    const size_t ir = ((size_t)NUM_USERS + items[b]) * 16 + l16;
    half4 a0 = x0[ur], a1 = x1[ur], a2 = x2[ur], a3 = x3[ur];
    half4 c0 = x0[ir], c1 = x1[ir], c2 = x2[ir], c3 = x3[ir];
    float p = 0.f;
#pragma unroll
    for (int j = 0; j < 4; ++j) {
        float su = (float)a0[j] + (float)a1[j] + (float)a2[j] + (float)a3[j];
        float si = (float)c0[j] + (float)c1[j] + (float)c2[j] + (float)c3[j];
        p += su * si;
    }
    p += __shfl_xor(p, 8);
    p += __shfl_xor(p, 4);
    p += __shfl_xor(p, 2);
    p += __shfl_xor(p, 1);
    if (l16 == 0) out[b] = p * (1.0f / 16.0f);
}

extern "C" void kernel_launch(void* const* d_in, const int* in_sizes, int n_in,
                              void* d_out, int out_size, void* d_ws, size_t ws_size,
                              hipStream_t stream) {
    const float* ue    = (const float*)d_in[0];
    const float* ie    = (const float*)d_in[1];
    const int*   rows  = (const int*)d_in[2];
    const int*   cols  = (const int*)d_in[3];
    const float* vals  = (const float*)d_in[4];
    const int*   users = (const int*)d_in[5];
    const int*   items = (const int*)d_in[6];
    float*       out   = (float*)d_out;

    // workspace layout: rowptr | x0 | x1 | x2 | x3 (all fp16, 19.2 MB each)
    char* ws = (char*)d_ws;
    size_t off = (((size_t)(NUM_NODES + 1) * sizeof(int)) + 255) & ~(size_t)255;
    const size_t halfbuf = (size_t)NUM_NODES * D * sizeof(_Float16);
    int*   rowptr = (int*)ws;
    half4* x0     = (half4*)(ws + off);
    half4* x1     = (half4*)(ws + off + 1 * halfbuf);
    half4* x2     = (half4*)(ws + off + 2 * halfbuf);
    half4* x3     = (half4*)(ws + off + 3 * halfbuf);

    k_rowptr<<<(NUM_NODES + 1 + 255) / 256, 256, 0, stream>>>(rows, rowptr);
    k_init<<<2048, 256, 0, stream>>>(ue, ie, x0);

    // 3 SpMM layers; 4 rows per wave, 4 waves per block -> 16 rows/block
    const int spmm_blocks = NUM_NODES / 16;   // 150000/16 = 9375 exact
    k_spmm<<<spmm_blocks, 256, 0, stream>>>(rowptr, cols, vals, x0, x1);
    k_spmm<<<spmm_blocks, 256, 0, stream>>>(rowptr, cols, vals, x1, x2);
    k_spmm<<<spmm_blocks, 256, 0, stream>>>(rowptr, cols, vals, x2, x3);

    // gamma: 4 elements per wave, 16 per block -> 256 blocks
    k_gamma<<<BATCH / 16, 256, 0, stream>>>(x0, x1, x2, x3, users, items, out);
}